// Round 12
// baseline (98.562 us; speedup 1.0000x reference)
//
#include <hip/hip_runtime.h>

// GPT-2 MHA forward on MI355X (gfx950).
// B=4 T=1024 C=1024 H=16 DH=64. fp32 in/out, bf16 MFMA internally.
//
// Pipeline:
//   cvt_x:      x fp32 -> bf16 XB [4096][1024]
//   cvt_w4:     {Wq(xQSCALE),Wk,Wv}->Wqkv^T, Wp->Wp^T (bf16)
//   gemm_qkv128: 128^2 tile BK=32, grid 768 = 3 blocks/CU, TRIPLE-buffered
//               LDS with counted vmcnt(4) (T4: prefetch depth 2, loads stay
//               in flight across barriers; 1 barrier/tile). Swizzled LDS.
//               Q,K -> QKVB rows; V -> VT[bh][d][t] directly.
//   attn:       causal flash attention, paired q-tiles, max-free exp2 softmax,
//               dual-step K/V fragment sharing -> XB
//   gemm_proj:  BM=64 BN=128 BK=32, same triple-buffer counted-vmcnt loop
//
// Workspace: 48 MB.

typedef unsigned short ushort_t;
typedef __attribute__((ext_vector_type(8))) __bf16 bf16x8;
typedef __attribute__((ext_vector_type(8))) unsigned short us8;
typedef __attribute__((ext_vector_type(4))) unsigned short us4;
typedef __attribute__((ext_vector_type(4))) float f32x4;

#define AS1 __attribute__((address_space(1)))
#define AS3 __attribute__((address_space(3)))

#define QSCALE 0.18033688011112042f   // 0.125 * log2(e)

__device__ __forceinline__ ushort_t f2bf(float f) {
  unsigned int u = __float_as_uint(f);
  u += 0x7fffu + ((u >> 16) & 1u);   // RTNE
  return (ushort_t)(u >> 16);
}

// native HW conversion (compiler packs pairs into v_cvt_pk_bf16_f32)
__device__ __forceinline__ ushort_t f2bf_hw(float f) {
  union { __bf16 b; ushort_t u; } cv;
  cv.b = (__bf16)f;
  return cv.u;
}

// ---------------- conversions ----------------

__global__ void cvt_x_kernel(const float* __restrict__ x, ushort_t* __restrict__ xb) {
  const int i = blockIdx.x * 256 + threadIdx.x;       // one float4 each
  const float4 v = reinterpret_cast<const float4*>(x)[i];
  us4 o;
  o.x = f2bf(v.x); o.y = f2bf(v.y); o.z = f2bf(v.z); o.w = f2bf(v.w);
  reinterpret_cast<us4*>(xb)[i] = o;
}

// z in 0..3 selects {Wq,Wk,Wv,Wp}; outputs transposed bf16.
// Wq is pre-scaled by QSCALE (DH^-0.5 and log2e folded; exp2 softmax).
__global__ void cvt_w4_kernel(const float* __restrict__ Wq, const float* __restrict__ Wk,
                              const float* __restrict__ Wv, const float* __restrict__ Wp,
                              ushort_t* __restrict__ WQKVT, ushort_t* __restrict__ WPT) {
  __shared__ float t[32][33];
  const int z = blockIdx.z;
  const float* W = (z == 0) ? Wq : (z == 1) ? Wk : (z == 2) ? Wv : Wp;
  ushort_t* Wt = (z == 3) ? WPT : (WQKVT + ((size_t)z << 20));
  const float wscale = (z == 0) ? QSCALE : 1.0f;
  const int n0 = blockIdx.x * 32, k0 = blockIdx.y * 32;
  const int tx = threadIdx.x, ty = threadIdx.y;
#pragma unroll
  for (int i = ty; i < 32; i += 8)
    t[i][tx] = W[(size_t)(k0 + i) * 1024 + n0 + tx];
  __syncthreads();
#pragma unroll
  for (int i = ty; i < 32; i += 8)
    Wt[(size_t)(n0 + i) * 1024 + k0 + tx] = f2bf(t[tx][i] * wscale);
}

// ---------------- QKV GEMM: 128x128, BK=32, 3-buffer counted-vmcnt --------
// C = XB[4096][1024] @ Wqkv (Bt[3072][1024]) + bias.
// 4 waves (2x2), wave tile 64x64. LDS: 3 buffers x (A 8KB + B 8KB) = 48KB
// -> 3 blocks/CU. Per tile t: stage(t+2) -> buf[(t+2)%3]; ds_read buf[t%3];
// 16 MFMA; vmcnt(4) [t+1's 4 loads landed, t+2's stay IN FLIGHT across the
// barrier]; s_barrier. Swizzle: 16B slot ^= row&3 on both gload source and
// ds_read (involution, rule #21) -> 2 lanes/bank.

__global__ __launch_bounds__(256, 3) void gemm_qkv128_kernel(
    const ushort_t* __restrict__ A, const ushort_t* __restrict__ Bt,
    const float* __restrict__ bq, const float* __restrict__ bk,
    const float* __restrict__ bv, ushort_t* __restrict__ QKVB,
    ushort_t* __restrict__ VT) {
  __shared__ ushort_t As[3][128 * 32];   // 3 x 8KB
  __shared__ ushort_t Bs[3][128 * 32];   // 3 x 8KB
  const int tid = threadIdx.x;
  const int wave = tid >> 6, lane = tid & 63;
  const int lgrp = lane >> 4, lmod = lane & 15;
  const int wr = wave >> 1, wc = wave & 1;
  // bijective XCD swizzle: 768 blocks, 96 per XCD
  const int swz = (blockIdx.x & 7) * 96 + (blockIdx.x >> 3);
  const int rowt = swz / 24, colt = swz % 24;
  const int row0 = rowt * 128, col0 = colt * 128;
  const bool isV = (colt >= 16);

  // staging: per op, 128 rows x 32 cols = 512 chunks of 16B (2/thread).
  // chunk c = i*256 + tid: row = i*64 + (tid>>2), slot = tid&3,
  // swizzled source slot = slot ^ (row&3).
  const int sslot = (tid & 3) ^ ((tid >> 2) & 3);
  const int srow = tid >> 2;            // 0..63, +64 for i=1

  auto stage = [&](int t) {
    const int buf = t % 3;
    const ushort_t* Asrc = A + (size_t)row0 * 1024 + t * 32 + sslot * 8;
    const ushort_t* Bsrc = Bt + (size_t)col0 * 1024 + t * 32 + sslot * 8;
#pragma unroll
    for (int i = 0; i < 2; ++i) {
      __builtin_amdgcn_global_load_lds(
          (AS1 void*)(Asrc + (size_t)(i * 64 + srow) * 1024),
          (AS3 void*)(As[buf] + (i * 256 + wave * 64) * 8), 16, 0, 0);
      __builtin_amdgcn_global_load_lds(
          (AS1 void*)(Bsrc + (size_t)(i * 64 + srow) * 1024),
          (AS3 void*)(Bs[buf] + (i * 256 + wave * 64) * 8), 16, 0, 0);
    }
  };

  f32x4 acc[4][4] = {};
  const int xs = lmod & 3;              // read-side swizzle (row&3 == lmod&3)

  // prologue: tiles 0,1 staged; wait tile 0 only (tile 1 stays in flight)
  stage(0);
  stage(1);
  asm volatile("s_waitcnt vmcnt(4)" ::: "memory");
  __builtin_amdgcn_s_barrier();

  for (int t = 0; t < 32; ++t) {
    if (t + 2 < 32) stage(t + 2);
    const ushort_t* cA = As[t % 3];
    const ushort_t* cB = Bs[t % 3];

    bf16x8 af[4], bfr[4];
#pragma unroll
    for (int mi = 0; mi < 4; ++mi)
      af[mi] = *reinterpret_cast<const bf16x8*>(
          &cA[(wr * 64 + mi * 16 + lmod) * 32 + (lgrp ^ xs) * 8]);
#pragma unroll
    for (int ni = 0; ni < 4; ++ni)
      bfr[ni] = *reinterpret_cast<const bf16x8*>(
          &cB[(wc * 64 + ni * 16 + lmod) * 32 + (lgrp ^ xs) * 8]);

    __builtin_amdgcn_s_setprio(1);
#pragma unroll
    for (int mi = 0; mi < 4; ++mi)
#pragma unroll
      for (int ni = 0; ni < 4; ++ni)
        acc[mi][ni] = __builtin_amdgcn_mfma_f32_16x16x32_bf16(
            af[mi], bfr[ni], acc[mi][ni], 0, 0, 0);
    __builtin_amdgcn_s_setprio(0);

    // counted wait: t+1's loads landed; t+2's remain outstanding
    if (t < 30) asm volatile("s_waitcnt vmcnt(4)" ::: "memory");
    else        asm volatile("s_waitcnt vmcnt(0)" ::: "memory");
    __builtin_amdgcn_s_barrier();
  }

  if (!isV) {
    // normal D: coalesced (consecutive lanes -> consecutive cols)
    const float* bsel = (col0 < 1024) ? bq : bk;
    const float bsc = (col0 < 1024) ? QSCALE : 1.0f;
    float bvv[4];
#pragma unroll
    for (int ni = 0; ni < 4; ++ni)
      bvv[ni] = bsel[(col0 & 1023) + wc * 64 + ni * 16 + lmod] * bsc;
#pragma unroll
    for (int mi = 0; mi < 4; ++mi) {
#pragma unroll
      for (int ni = 0; ni < 4; ++ni) {
        const int col = col0 + wc * 64 + ni * 16 + lmod;
#pragma unroll
        for (int r = 0; r < 4; ++r) {
          const int row = row0 + wr * 64 + mi * 16 + lgrp * 4 + r;
          QKVB[(size_t)row * 3072 + col] = f2bf(acc[mi][ni][r] + bvv[ni]);
        }
      }
    }
  } else {
    // V: lane -> col hd, 4 consecutive tokens per quad -> VT[bh][d][t]
    float bvv[4];
#pragma unroll
    for (int ni = 0; ni < 4; ++ni)
      bvv[ni] = bv[(col0 - 2048) + wc * 64 + ni * 16 + lmod];
#pragma unroll
    for (int mi = 0; mi < 4; ++mi) {
#pragma unroll
      for (int ni = 0; ni < 4; ++ni) {
        const int hd = (col0 - 2048) + wc * 64 + ni * 16 + lmod;
        const int R = row0 + wr * 64 + mi * 16 + lgrp * 4;
        const int bb = R >> 10, tl = R & 1023;
        us4 o;
#pragma unroll
        for (int r = 0; r < 4; ++r) o[r] = f2bf(acc[mi][ni][r] + bvv[ni]);
        *reinterpret_cast<us4*>(VT + ((size_t)(bb * 16 + (hd >> 6)) * 64 + (hd & 63)) * 1024 + tl) = o;
      }
    }
  }
}

// ---------------- out-proj GEMM: BM=64, BN=128, BK=32, 3-buffer ----------

__global__ __launch_bounds__(256, 2) void gemm_proj_kernel(
    const ushort_t* __restrict__ A, const ushort_t* __restrict__ Bt,
    const float* __restrict__ bias, float* __restrict__ Cout) {
  __shared__ ushort_t As[3][64 * 32];    // 3 x 4KB
  __shared__ ushort_t Bs[3][128 * 32];   // 3 x 8KB
  const int tid = threadIdx.x;
  const int wave = tid >> 6, lane = tid & 63;
  const int lgrp = lane >> 4, lmod = lane & 15;
  const int wr = wave >> 1, wc = wave & 1;
  const int swz = (blockIdx.x & 7) * 64 + (blockIdx.x >> 3);  // 512 blocks
  const int row0 = (swz >> 3) * 64, col0 = (swz & 7) * 128;

  const int sslot = (tid & 3) ^ ((tid >> 2) & 3);
  const int srow = tid >> 2;

  // A: 256 chunks (1/thread), B: 512 chunks (2/thread) -> 3 loads/thread
  auto stage = [&](int t) {
    const int buf = t % 3;
    const ushort_t* Asrc = A + (size_t)row0 * 1024 + t * 32 + sslot * 8;
    const ushort_t* Bsrc = Bt + (size_t)col0 * 1024 + t * 32 + sslot * 8;
    __builtin_amdgcn_global_load_lds(
        (AS1 void*)(Asrc + (size_t)srow * 1024),
        (AS3 void*)(As[buf] + (wave * 64) * 8), 16, 0, 0);
#pragma unroll
    for (int i = 0; i < 2; ++i)
      __builtin_amdgcn_global_load_lds(
          (AS1 void*)(Bsrc + (size_t)(i * 64 + srow) * 1024),
          (AS3 void*)(Bs[buf] + (i * 256 + wave * 64) * 8), 16, 0, 0);
  };

  f32x4 acc[2][4] = {};
  const int xs = lmod & 3;

  stage(0);
  stage(1);
  asm volatile("s_waitcnt vmcnt(3)" ::: "memory");
  __builtin_amdgcn_s_barrier();

  for (int t = 0; t < 32; ++t) {
    if (t + 2 < 32) stage(t + 2);
    const ushort_t* cA = As[t % 3];
    const ushort_t* cB = Bs[t % 3];

    bf16x8 af[2], bfr[4];
#pragma unroll
    for (int mi = 0; mi < 2; ++mi)
      af[mi] = *reinterpret_cast<const bf16x8*>(
          &cA[(wr * 32 + mi * 16 + lmod) * 32 + (lgrp ^ xs) * 8]);
#pragma unroll
    for (int ni = 0; ni < 4; ++ni)
      bfr[ni] = *reinterpret_cast<const bf16x8*>(
          &cB[(wc * 64 + ni * 16 + lmod) * 32 + (lgrp ^ xs) * 8]);

    __builtin_amdgcn_s_setprio(1);
#pragma unroll
    for (int mi = 0; mi < 2; ++mi)
#pragma unroll
      for (int ni = 0; ni < 4; ++ni)
        acc[mi][ni] = __builtin_amdgcn_mfma_f32_16x16x32_bf16(
            af[mi], bfr[ni], acc[mi][ni], 0, 0, 0);
    __builtin_amdgcn_s_setprio(0);

    if (t < 30) asm volatile("s_waitcnt vmcnt(3)" ::: "memory");
    else        asm volatile("s_waitcnt vmcnt(0)" ::: "memory");
    __builtin_amdgcn_s_barrier();
  }

  float bvv[4];
#pragma unroll
  for (int ni = 0; ni < 4; ++ni) bvv[ni] = bias[col0 + wc * 64 + ni * 16 + lmod];
#pragma unroll
  for (int mi = 0; mi < 2; ++mi)
#pragma unroll
    for (int ni = 0; ni < 4; ++ni) {
      const int col = col0 + wc * 64 + ni * 16 + lmod;
#pragma unroll
      for (int r = 0; r < 4; ++r) {
        const int row = row0 + wr * 32 + mi * 16 + lgrp * 4 + r;
        Cout[(size_t)row * 1024 + col] = acc[mi][ni][r] + bvv[ni];
      }
    }
}

// ---------------- causal flash attention, paired q-tiles ----------------
// grid 512 = 8 pairs x 64 bh; q-tiles p and 15-p per block, 17 steps each.
// Max-free exp2 softmax (scores bounded; log2e folded into Wq), deferred
// l-reduce. On iterations j<=p both q-tiles are active: step_dual shares
// every K/V fragment read between them (2 MFMAs per ds_read).

__global__ __launch_bounds__(256, 2) void attn_kernel(
    const ushort_t* __restrict__ QKV, const ushort_t* __restrict__ VT,
    ushort_t* __restrict__ Og) {
  const int bid = blockIdx.x;
  const int swz = (bid & 7) * 64 + (bid >> 3);   // XCD-chunked
  const int p = swz & 7, bh = swz >> 3;
  const int b = bh >> 4, h = bh & 15;
  const int jmax = 15 - p;
  const int tid = threadIdx.x;
  const int wave = tid >> 6, lane = tid & 63;
  const int lgrp = lane >> 4, lmod = lane & 15;

  __shared__ ushort_t Ks[64 * 72];        // K tile [kc][dh], +8 pad
  __shared__ ushort_t Vs[64 * 72];        // V^T tile [dh][kc], +8 pad
  __shared__ ushort_t Ps[4][2][16 * 72];  // per-wave P, [lo/hi]

  const size_t xrow0 = (size_t)b * 1024;
  const int qlo = p * 64 + wave * 16;
  const int qhi = jmax * 64 + wave * 16;

  bf16x8 qfl[2], qfh[2];
#pragma unroll
  for (int ks = 0; ks < 2; ++ks) {
    qfl[ks] = *reinterpret_cast<const bf16x8*>(
        QKV + (xrow0 + qlo + lmod) * 3072 + h * 64 + ks * 32 + lgrp * 8);
    qfh[ks] = *reinterpret_cast<const bf16x8*>(
        QKV + (xrow0 + qhi + lmod) * 3072 + h * 64 + ks * 32 + lgrp * 8);
  }

  f32x4 ol[4] = {}, oh[4] = {};
  float ll[4] = {0.f, 0.f, 0.f, 0.f}, lh[4] = {0.f, 0.f, 0.f, 0.f};

  const int sr = tid >> 3;
  const int scc = (tid & 7) << 3;
  us8 kreg0, kreg1, vreg0, vreg1;

  auto load_tile = [&](int j) {
    const ushort_t* kp = QKV + (xrow0 + j * 64 + sr) * 3072 + 1024 + h * 64 + scc;
    kreg0 = *reinterpret_cast<const us8*>(kp);
    kreg1 = *reinterpret_cast<const us8*>(kp + 32 * 3072);
    const ushort_t* vp = VT + ((size_t)bh * 64 + sr) * 1024 + j * 64 + scc;
    vreg0 = *reinterpret_cast<const us8*>(vp);
    vreg1 = *reinterpret_cast<const us8*>(vp + 32 * 1024);
  };
  auto write_tile = [&]() {
    *reinterpret_cast<us8*>(&Ks[sr * 72 + scc]) = kreg0;
    *reinterpret_cast<us8*>(&Ks[(32 + sr) * 72 + scc]) = kreg1;
    *reinterpret_cast<us8*>(&Vs[sr * 72 + scc]) = vreg0;
    *reinterpret_cast<us8*>(&Vs[(32 + sr) * 72 + scc]) = vreg1;
  };

  // masking helper (diag tile: kcol > qrow -> -inf)
  auto mask_diag = [&](f32x4* s) {
    const int qloc = wave * 16 + lgrp * 4;
#pragma unroll
    for (int cg = 0; cg < 4; ++cg) {
      const int kcol = cg * 16 + lmod;
#pragma unroll
      for (int r = 0; r < 4; ++r)
        if (kcol > qloc + r) s[cg][r] = -1e30f;
    }
  };

  // single-tile step (hi tile on iterations j > p)
  auto step = [&](const bf16x8* qf, f32x4* oacc, float* lsum, bool diag) {
    f32x4 s[4];
    __builtin_amdgcn_s_setprio(1);
#pragma unroll
    for (int cg = 0; cg < 4; ++cg) {
      f32x4 a = {};
#pragma unroll
      for (int ks = 0; ks < 2; ++ks) {
        bf16x8 kf = *reinterpret_cast<const bf16x8*>(
            &Ks[(cg * 16 + lmod) * 72 + ks * 32 + lgrp * 8]);
        a = __builtin_amdgcn_mfma_f32_16x16x32_bf16(qf[ks], kf, a, 0, 0, 0);
      }
      s[cg] = a;
    }
    __builtin_amdgcn_s_setprio(0);
    if (diag) mask_diag(s);
#pragma unroll
    for (int cg = 0; cg < 4; ++cg)
#pragma unroll
      for (int r = 0; r < 4; ++r) s[cg][r] = exp2f(s[cg][r]);
#pragma unroll
    for (int r = 0; r < 4; ++r)
      lsum[r] += (s[0][r] + s[1][r]) + (s[2][r] + s[3][r]);
#pragma unroll
    for (int cg = 0; cg < 4; ++cg)
#pragma unroll
      for (int r = 0; r < 4; ++r)
        Ps[wave][1][(lgrp * 4 + r) * 72 + cg * 16 + lmod] = f2bf_hw(s[cg][r]);
    __builtin_amdgcn_s_setprio(1);
#pragma unroll
    for (int ks = 0; ks < 2; ++ks) {
      bf16x8 pf = *reinterpret_cast<const bf16x8*>(
          &Ps[wave][1][lmod * 72 + ks * 32 + lgrp * 8]);
#pragma unroll
      for (int dhg = 0; dhg < 4; ++dhg) {
        bf16x8 vf = *reinterpret_cast<const bf16x8*>(
            &Vs[(dhg * 16 + lmod) * 72 + ks * 32 + lgrp * 8]);
        oacc[dhg] = __builtin_amdgcn_mfma_f32_16x16x32_bf16(pf, vf, oacc[dhg], 0, 0, 0);
      }
    }
    __builtin_amdgcn_s_setprio(0);
  };

  // dual step: both q-tiles share every K/V fragment (j <= p; diag_lo = j==p)
  auto step_dual = [&](bool diag_lo) {
    f32x4 sl[4], sh[4];
    __builtin_amdgcn_s_setprio(1);
#pragma unroll
    for (int cg = 0; cg < 4; ++cg) {
      f32x4 al = {}, ah = {};
#pragma unroll
      for (int ks = 0; ks < 2; ++ks) {
        bf16x8 kf = *reinterpret_cast<const bf16x8*>(
            &Ks[(cg * 16 + lmod) * 72 + ks * 32 + lgrp * 8]);
        al = __builtin_amdgcn_mfma_f32_16x16x32_bf16(qfl[ks], kf, al, 0, 0, 0);
        ah = __builtin_amdgcn_mfma_f32_16x16x32_bf16(qfh[ks], kf, ah, 0, 0, 0);
      }
      sl[cg] = al; sh[cg] = ah;
    }
    __builtin_amdgcn_s_setprio(0);
    if (diag_lo) mask_diag(sl);          // hi tile never diagonal here (p < jmax)
#pragma unroll
    for (int cg = 0; cg < 4; ++cg)
#pragma unroll
      for (int r = 0; r < 4; ++r) {
        sl[cg][r] = exp2f(sl[cg][r]);
        sh[cg][r] = exp2f(sh[cg][r]);
      }
#pragma unroll
    for (int r = 0; r < 4; ++r) {
      ll[r] += (sl[0][r] + sl[1][r]) + (sl[2][r] + sl[3][r]);
      lh[r] += (sh[0][r] + sh[1][r]) + (sh[2][r] + sh[3][r]);
    }
#pragma unroll
    for (int cg = 0; cg < 4; ++cg)
#pragma unroll
      for (int r = 0; r < 4; ++r) {
        Ps[wave][0][(lgrp * 4 + r) * 72 + cg * 16 + lmod] = f2bf_hw(sl[cg][r]);
        Ps[wave][1][(lgrp * 4 + r) * 72 + cg * 16 + lmod] = f2bf_hw(sh[cg][r]);
      }
    __builtin_amdgcn_s_setprio(1);
#pragma unroll
    for (int ks = 0; ks < 2; ++ks) {
      bf16x8 pfl = *reinterpret_cast<const bf16x8*>(
          &Ps[wave][0][lmod * 72 + ks * 32 + lgrp * 8]);
      bf16x8 pfh = *reinterpret_cast<const bf16x8*>(
          &Ps[wave][1][lmod * 72 + ks * 32 + lgrp * 8]);
#pragma unroll
      for (int dhg = 0; dhg < 4; ++dhg) {
        bf16x8 vf = *reinterpret_cast<const bf16x8*>(
            &Vs[(dhg * 16 + lmod) * 72 + ks * 32 + lgrp * 8]);
        ol[dhg] = __builtin_amdgcn_mfma_f32_16x16x32_bf16(pfl, vf, ol[dhg], 0, 0, 0);
        oh[dhg] = __builtin_amdgcn_mfma_f32_16x16x32_bf16(pfh, vf, oh[dhg], 0, 0, 0);
      }
    }
    __builtin_amdgcn_s_setprio(0);
  };

  load_tile(0);
  for (int j = 0; j <= jmax; ++j) {
    __syncthreads();
    write_tile();
    __syncthreads();
    if (j < jmax) load_tile(j + 1);
    if (j <= p) step_dual(j == p);       // block-uniform branch
    else step(qfh, oh, lh, j == jmax);
  }

#pragma unroll
  for (int m = 1; m <= 8; m <<= 1)
#pragma unroll
    for (int r = 0; r < 4; ++r) {
      ll[r] += __shfl_xor(ll[r], m);
      lh[r] += __shfl_xor(lh[r], m);
    }

#pragma unroll
  for (int dhg = 0; dhg < 4; ++dhg) {
    const int col = h * 64 + dhg * 16 + lmod;
#pragma unroll
    for (int r = 0; r < 4; ++r) {
      Og[(xrow0 + qlo + lgrp * 4 + r) * 1024 + col] = f2bf_hw(ol[dhg][r] / ll[r]);
      Og[(xrow0 + qhi + lgrp * 4 + r) * 1024 + col] = f2bf_hw(oh[dhg][r] / lh[r]);
    }
  }
}

// ---------------- launch ----------------

extern "C" void kernel_launch(void* const* d_in, const int* in_sizes, int n_in,
                              void* d_out, int out_size, void* d_ws, size_t ws_size,
                              hipStream_t stream) {
  const float* x  = (const float*)d_in[0];
  const float* Wq = (const float*)d_in[1];
  const float* bq = (const float*)d_in[2];
  const float* Wk = (const float*)d_in[3];
  const float* bk = (const float*)d_in[4];
  const float* Wv = (const float*)d_in[5];
  const float* bv = (const float*)d_in[6];
  const float* Wp = (const float*)d_in[7];
  const float* bp = (const float*)d_in[8];
  float* out = (float*)d_out;

  char* ws = (char*)d_ws;
  ushort_t* XB    = (ushort_t*)(ws);                  // 8MB; reused as ctx
  ushort_t* WQKVT = (ushort_t*)(ws + ( 8ull << 20));  // 6MB [3072][1024]
  ushort_t* WPT   = (ushort_t*)(ws + (14ull << 20));  // 2MB [1024][1024]
  ushort_t* QKVB  = (ushort_t*)(ws + (16ull << 20));  // 24MB [4096][3072] (V region unused)
  ushort_t* VT    = (ushort_t*)(ws + (40ull << 20));  // 8MB [64bh][64d][1024t]

  cvt_x_kernel<<<4096, 256, 0, stream>>>(x, XB);
  cvt_w4_kernel<<<dim3(32, 32, 4), dim3(32, 8), 0, stream>>>(Wq, Wk, Wv, Wp, WQKVT, WPT);
  gemm_qkv128_kernel<<<768, 256, 0, stream>>>(XB, WQKVT, bq, bk, bv, QKVB, VT);
  attn_kernel<<<512, 256, 0, stream>>>(QKVB, VT, XB);
  gemm_proj_kernel<<<512, 256, 0, stream>>>(XB, WPT, bp, out);
}

// Round 13
// 86.483 us; speedup vs baseline: 1.1397x; 1.1397x over previous
//
#include <hip/hip_runtime.h>

// GPT-2 MHA forward on MI355X (gfx950).
// B=4 T=1024 C=1024 H=16 DH=64. fp32 in/out, bf16 MFMA internally.
//
// Pipeline (4 dispatches):
//   cvt_fused:  x fp32 -> bf16 XB; {Wq(xQSCALE),Wk,Wv,Wp} -> transposed bf16
//   gemm_qkv128: 128^2 tile BK=64, grid 768 = 3 blocks/CU co-resident,
//               swizzled LDS (0 conflicts), coalesced normal-D epilogues.
//               Q,K -> QKVB rows; V -> VT[bh][d][t] directly.
//   attn:       causal flash attention, paired q-tiles, max-free exp2 softmax,
//               dual-step K/V fragment sharing -> XB
//   gemm_proj:  BM=64 BN=128 BK=64, coalesced fp32 stores
//
// Workspace: 48 MB.

typedef unsigned short ushort_t;
typedef __attribute__((ext_vector_type(8))) __bf16 bf16x8;
typedef __attribute__((ext_vector_type(8))) unsigned short us8;
typedef __attribute__((ext_vector_type(4))) unsigned short us4;
typedef __attribute__((ext_vector_type(4))) float f32x4;

#define AS1 __attribute__((address_space(1)))
#define AS3 __attribute__((address_space(3)))

#define QSCALE 0.18033688011112042f   // 0.125 * log2(e)

__device__ __forceinline__ ushort_t f2bf(float f) {
  unsigned int u = __float_as_uint(f);
  u += 0x7fffu + ((u >> 16) & 1u);   // RTNE
  return (ushort_t)(u >> 16);
}

// native HW conversion (compiler packs pairs into v_cvt_pk_bf16_f32)
__device__ __forceinline__ ushort_t f2bf_hw(float f) {
  union { __bf16 b; ushort_t u; } cv;
  cv.b = (__bf16)f;
  return cv.u;
}

// ---------------- fused conversions ----------------
// blocks 0..4095: x fp32 -> bf16 (one float4/thread).
// blocks 4096..8191: one 32x32 transpose tile of {Wq,Wk,Wv,Wp} each.

__global__ void cvt_fused_kernel(const float* __restrict__ x,
                                 const float* __restrict__ Wq, const float* __restrict__ Wk,
                                 const float* __restrict__ Wv, const float* __restrict__ Wp,
                                 ushort_t* __restrict__ XB,
                                 ushort_t* __restrict__ WQKVT, ushort_t* __restrict__ WPT) {
  const int tid = threadIdx.x;
  if (blockIdx.x < 4096) {
    const int i = blockIdx.x * 256 + tid;
    const float4 v = reinterpret_cast<const float4*>(x)[i];
    us4 o;
    o.x = f2bf(v.x); o.y = f2bf(v.y); o.z = f2bf(v.z); o.w = f2bf(v.w);
    reinterpret_cast<us4*>(XB)[i] = o;
    return;
  }
  __shared__ float t[32][33];
  const int tt = blockIdx.x - 4096;     // 0..4095
  const int z = tt >> 10;               // matrix 0..3
  const int tile = tt & 1023;
  const int n0 = (tile & 31) * 32, k0 = (tile >> 5) * 32;
  const float* W = (z == 0) ? Wq : (z == 1) ? Wk : (z == 2) ? Wv : Wp;
  ushort_t* Wt = (z == 3) ? WPT : (WQKVT + ((size_t)z << 20));
  const float wscale = (z == 0) ? QSCALE : 1.0f;
  const int tx = tid & 31, ty = tid >> 5;   // 32 x 8
#pragma unroll
  for (int i = ty; i < 32; i += 8)
    t[i][tx] = W[(size_t)(k0 + i) * 1024 + n0 + tx];
  __syncthreads();
#pragma unroll
  for (int i = ty; i < 32; i += 8)
    Wt[(size_t)(n0 + i) * 1024 + k0 + tx] = f2bf(t[tx][i] * wscale);
}

// ---------------- QKV GEMM: 128x128, BK=64, grid 768 (3 blocks/CU) --------

__global__ __launch_bounds__(256, 3) void gemm_qkv128_kernel(
    const ushort_t* __restrict__ A, const ushort_t* __restrict__ Bt,
    const float* __restrict__ bq, const float* __restrict__ bk,
    const float* __restrict__ bv, ushort_t* __restrict__ QKVB,
    ushort_t* __restrict__ VT) {
  __shared__ ushort_t As[128 * 64];   // 16KB
  __shared__ ushort_t Bs[128 * 64];   // 16KB
  const int tid = threadIdx.x;
  const int wave = tid >> 6, lane = tid & 63;
  const int lgrp = lane >> 4, lmod = lane & 15;
  const int wr = wave >> 1, wc = wave & 1;
  // bijective XCD swizzle: 768 blocks, 96 per XCD
  const int swz = (blockIdx.x & 7) * 96 + (blockIdx.x >> 3);
  const int rowt = swz / 24, colt = swz % 24;
  const int row0 = rowt * 128, col0 = colt * 128;
  const bool isV = (colt >= 16);

  const int sslot = (tid & 7) ^ ((tid >> 3) & 7);
  const int srow = tid >> 3;          // 0..31, +32 per i

  auto stage = [&](int t) {
    const ushort_t* Asrc = A + (size_t)row0 * 1024 + t * 64 + sslot * 8;
    const ushort_t* Bsrc = Bt + (size_t)col0 * 1024 + t * 64 + sslot * 8;
#pragma unroll
    for (int i = 0; i < 4; ++i) {
      __builtin_amdgcn_global_load_lds(
          (AS1 void*)(Asrc + (size_t)(i * 32 + srow) * 1024),
          (AS3 void*)(As + (i * 256 + wave * 64) * 8), 16, 0, 0);
      __builtin_amdgcn_global_load_lds(
          (AS1 void*)(Bsrc + (size_t)(i * 32 + srow) * 1024),
          (AS3 void*)(Bs + (i * 256 + wave * 64) * 8), 16, 0, 0);
    }
  };

  f32x4 acc[4][4] = {};
  const int xm = lmod & 7;

  for (int t = 0; t < 16; ++t) {
    stage(t);
    asm volatile("s_waitcnt vmcnt(0)" ::: "memory");
    __builtin_amdgcn_s_barrier();     // tile visible

    bf16x8 af[4][2], bfr[4][2];
#pragma unroll
    for (int mi = 0; mi < 4; ++mi)
#pragma unroll
      for (int ks = 0; ks < 2; ++ks)
        af[mi][ks] = *reinterpret_cast<const bf16x8*>(
            &As[(wr * 64 + mi * 16 + lmod) * 64 + (((ks << 2) | lgrp) ^ xm) * 8]);
#pragma unroll
    for (int ni = 0; ni < 4; ++ni)
#pragma unroll
      for (int ks = 0; ks < 2; ++ks)
        bfr[ni][ks] = *reinterpret_cast<const bf16x8*>(
            &Bs[(wc * 64 + ni * 16 + lmod) * 64 + (((ks << 2) | lgrp) ^ xm) * 8]);

    __builtin_amdgcn_s_setprio(1);
#pragma unroll
    for (int mi = 0; mi < 4; ++mi)
#pragma unroll
      for (int ni = 0; ni < 4; ++ni)
#pragma unroll
        for (int ks = 0; ks < 2; ++ks)
          acc[mi][ni] = __builtin_amdgcn_mfma_f32_16x16x32_bf16(
              af[mi][ks], bfr[ni][ks], acc[mi][ni], 0, 0, 0);
    __builtin_amdgcn_s_setprio(0);
    __builtin_amdgcn_s_barrier();     // readers done; next stage may overwrite
  }

  if (!isV) {
    // normal D: coalesced (consecutive lanes -> consecutive cols)
    const float* bsel = (col0 < 1024) ? bq : bk;
    const float bsc = (col0 < 1024) ? QSCALE : 1.0f;
    float bvv[4];
#pragma unroll
    for (int ni = 0; ni < 4; ++ni)
      bvv[ni] = bsel[(col0 & 1023) + wc * 64 + ni * 16 + lmod] * bsc;
#pragma unroll
    for (int mi = 0; mi < 4; ++mi) {
#pragma unroll
      for (int ni = 0; ni < 4; ++ni) {
        const int col = col0 + wc * 64 + ni * 16 + lmod;
#pragma unroll
        for (int r = 0; r < 4; ++r) {
          const int row = row0 + wr * 64 + mi * 16 + lgrp * 4 + r;
          QKVB[(size_t)row * 3072 + col] = f2bf(acc[mi][ni][r] + bvv[ni]);
        }
      }
    }
  } else {
    // V: lane -> col hd, 4 consecutive tokens per quad -> VT[bh][d][t]
    float bvv[4];
#pragma unroll
    for (int ni = 0; ni < 4; ++ni)
      bvv[ni] = bv[(col0 - 2048) + wc * 64 + ni * 16 + lmod];
#pragma unroll
    for (int mi = 0; mi < 4; ++mi) {
#pragma unroll
      for (int ni = 0; ni < 4; ++ni) {
        const int hd = (col0 - 2048) + wc * 64 + ni * 16 + lmod;
        const int R = row0 + wr * 64 + mi * 16 + lgrp * 4;
        const int bb = R >> 10, tl = R & 1023;
        us4 o;
#pragma unroll
        for (int r = 0; r < 4; ++r) o[r] = f2bf(acc[mi][ni][r] + bvv[ni]);
        *reinterpret_cast<us4*>(VT + ((size_t)(bb * 16 + (hd >> 6)) * 64 + (hd & 63)) * 1024 + tl) = o;
      }
    }
  }
}

// ---------------- out-proj GEMM: BM=64, BN=128, BK=64 ----------------

__global__ __launch_bounds__(256, 2) void gemm_proj_kernel(
    const ushort_t* __restrict__ A, const ushort_t* __restrict__ Bt,
    const float* __restrict__ bias, float* __restrict__ Cout) {
  __shared__ ushort_t As[64 * 64];    // 8KB
  __shared__ ushort_t Bs[128 * 64];   // 16KB
  const int tid = threadIdx.x;
  const int wave = tid >> 6, lane = tid & 63;
  const int lgrp = lane >> 4, lmod = lane & 15;
  const int wr = wave >> 1, wc = wave & 1;
  const int swz = (blockIdx.x & 7) * 64 + (blockIdx.x >> 3);  // 512 blocks
  const int row0 = (swz >> 3) * 64, col0 = (swz & 7) * 128;

  const int sslot = (tid & 7) ^ ((tid >> 3) & 7);
  const int srow = tid >> 3;

  auto stage = [&](int t) {
    const ushort_t* Asrc = A + (size_t)row0 * 1024 + t * 64 + sslot * 8;
    const ushort_t* Bsrc = Bt + (size_t)col0 * 1024 + t * 64 + sslot * 8;
#pragma unroll
    for (int i = 0; i < 2; ++i)       // A: 512 chunks
      __builtin_amdgcn_global_load_lds(
          (AS1 void*)(Asrc + (size_t)(i * 32 + srow) * 1024),
          (AS3 void*)(As + (i * 256 + wave * 64) * 8), 16, 0, 0);
#pragma unroll
    for (int i = 0; i < 4; ++i)       // B: 1024 chunks
      __builtin_amdgcn_global_load_lds(
          (AS1 void*)(Bsrc + (size_t)(i * 32 + srow) * 1024),
          (AS3 void*)(Bs + (i * 256 + wave * 64) * 8), 16, 0, 0);
  };

  f32x4 acc[2][4] = {};
  const int xm = lmod & 7;

  for (int t = 0; t < 16; ++t) {
    stage(t);
    asm volatile("s_waitcnt vmcnt(0)" ::: "memory");
    __builtin_amdgcn_s_barrier();

    bf16x8 af[2][2], bfr[4][2];
#pragma unroll
    for (int mi = 0; mi < 2; ++mi)
#pragma unroll
      for (int ks = 0; ks < 2; ++ks)
        af[mi][ks] = *reinterpret_cast<const bf16x8*>(
            &As[(wr * 32 + mi * 16 + lmod) * 64 + (((ks << 2) | lgrp) ^ xm) * 8]);
#pragma unroll
    for (int ni = 0; ni < 4; ++ni)
#pragma unroll
      for (int ks = 0; ks < 2; ++ks)
        bfr[ni][ks] = *reinterpret_cast<const bf16x8*>(
            &Bs[(wc * 64 + ni * 16 + lmod) * 64 + (((ks << 2) | lgrp) ^ xm) * 8]);

    __builtin_amdgcn_s_setprio(1);
#pragma unroll
    for (int mi = 0; mi < 2; ++mi)
#pragma unroll
      for (int ni = 0; ni < 4; ++ni)
#pragma unroll
        for (int ks = 0; ks < 2; ++ks)
          acc[mi][ni] = __builtin_amdgcn_mfma_f32_16x16x32_bf16(
              af[mi][ks], bfr[ni][ks], acc[mi][ni], 0, 0, 0);
    __builtin_amdgcn_s_setprio(0);
    __builtin_amdgcn_s_barrier();
  }

  float bvv[4];
#pragma unroll
  for (int ni = 0; ni < 4; ++ni) bvv[ni] = bias[col0 + wc * 64 + ni * 16 + lmod];
#pragma unroll
  for (int mi = 0; mi < 2; ++mi)
#pragma unroll
    for (int ni = 0; ni < 4; ++ni) {
      const int col = col0 + wc * 64 + ni * 16 + lmod;
#pragma unroll
      for (int r = 0; r < 4; ++r) {
        const int row = row0 + wr * 32 + mi * 16 + lgrp * 4 + r;
        Cout[(size_t)row * 1024 + col] = acc[mi][ni][r] + bvv[ni];
      }
    }
}

// ---------------- causal flash attention, paired q-tiles ----------------
// grid 512 = 8 pairs x 64 bh; q-tiles p and 15-p per block, 17 steps each.
// Max-free exp2 softmax (scores bounded; log2e folded into Wq), deferred
// l-reduce. On iterations j<=p both q-tiles are active: step_dual shares
// every K/V fragment read between them (2 MFMAs per ds_read).

__global__ __launch_bounds__(256, 2) void attn_kernel(
    const ushort_t* __restrict__ QKV, const ushort_t* __restrict__ VT,
    ushort_t* __restrict__ Og) {
  const int bid = blockIdx.x;
  const int swz = (bid & 7) * 64 + (bid >> 3);   // XCD-chunked
  const int p = swz & 7, bh = swz >> 3;
  const int b = bh >> 4, h = bh & 15;
  const int jmax = 15 - p;
  const int tid = threadIdx.x;
  const int wave = tid >> 6, lane = tid & 63;
  const int lgrp = lane >> 4, lmod = lane & 15;

  __shared__ ushort_t Ks[64 * 72];        // K tile [kc][dh], +8 pad
  __shared__ ushort_t Vs[64 * 72];        // V^T tile [dh][kc], +8 pad
  __shared__ ushort_t Ps[4][2][16 * 72];  // per-wave P, [lo/hi]

  const size_t xrow0 = (size_t)b * 1024;
  const int qlo = p * 64 + wave * 16;
  const int qhi = jmax * 64 + wave * 16;

  bf16x8 qfl[2], qfh[2];
#pragma unroll
  for (int ks = 0; ks < 2; ++ks) {
    qfl[ks] = *reinterpret_cast<const bf16x8*>(
        QKV + (xrow0 + qlo + lmod) * 3072 + h * 64 + ks * 32 + lgrp * 8);
    qfh[ks] = *reinterpret_cast<const bf16x8*>(
        QKV + (xrow0 + qhi + lmod) * 3072 + h * 64 + ks * 32 + lgrp * 8);
  }

  f32x4 ol[4] = {}, oh[4] = {};
  float ll[4] = {0.f, 0.f, 0.f, 0.f}, lh[4] = {0.f, 0.f, 0.f, 0.f};

  const int sr = tid >> 3;
  const int scc = (tid & 7) << 3;
  us8 kreg0, kreg1, vreg0, vreg1;

  auto load_tile = [&](int j) {
    const ushort_t* kp = QKV + (xrow0 + j * 64 + sr) * 3072 + 1024 + h * 64 + scc;
    kreg0 = *reinterpret_cast<const us8*>(kp);
    kreg1 = *reinterpret_cast<const us8*>(kp + 32 * 3072);
    const ushort_t* vp = VT + ((size_t)bh * 64 + sr) * 1024 + j * 64 + scc;
    vreg0 = *reinterpret_cast<const us8*>(vp);
    vreg1 = *reinterpret_cast<const us8*>(vp + 32 * 1024);
  };
  auto write_tile = [&]() {
    *reinterpret_cast<us8*>(&Ks[sr * 72 + scc]) = kreg0;
    *reinterpret_cast<us8*>(&Ks[(32 + sr) * 72 + scc]) = kreg1;
    *reinterpret_cast<us8*>(&Vs[sr * 72 + scc]) = vreg0;
    *reinterpret_cast<us8*>(&Vs[(32 + sr) * 72 + scc]) = vreg1;
  };

  // masking helper (diag tile: kcol > qrow -> -inf)
  auto mask_diag = [&](f32x4* s) {
    const int qloc = wave * 16 + lgrp * 4;
#pragma unroll
    for (int cg = 0; cg < 4; ++cg) {
      const int kcol = cg * 16 + lmod;
#pragma unroll
      for (int r = 0; r < 4; ++r)
        if (kcol > qloc + r) s[cg][r] = -1e30f;
    }
  };

  // single-tile step (hi tile on iterations j > p)
  auto step = [&](const bf16x8* qf, f32x4* oacc, float* lsum, bool diag) {
    f32x4 s[4];
    __builtin_amdgcn_s_setprio(1);
#pragma unroll
    for (int cg = 0; cg < 4; ++cg) {
      f32x4 a = {};
#pragma unroll
      for (int ks = 0; ks < 2; ++ks) {
        bf16x8 kf = *reinterpret_cast<const bf16x8*>(
            &Ks[(cg * 16 + lmod) * 72 + ks * 32 + lgrp * 8]);
        a = __builtin_amdgcn_mfma_f32_16x16x32_bf16(qf[ks], kf, a, 0, 0, 0);
      }
      s[cg] = a;
    }
    __builtin_amdgcn_s_setprio(0);
    if (diag) mask_diag(s);
#pragma unroll
    for (int cg = 0; cg < 4; ++cg)
#pragma unroll
      for (int r = 0; r < 4; ++r) s[cg][r] = exp2f(s[cg][r]);
#pragma unroll
    for (int r = 0; r < 4; ++r)
      lsum[r] += (s[0][r] + s[1][r]) + (s[2][r] + s[3][r]);
#pragma unroll
    for (int cg = 0; cg < 4; ++cg)
#pragma unroll
      for (int r = 0; r < 4; ++r)
        Ps[wave][1][(lgrp * 4 + r) * 72 + cg * 16 + lmod] = f2bf_hw(s[cg][r]);
    __builtin_amdgcn_s_setprio(1);
#pragma unroll
    for (int ks = 0; ks < 2; ++ks) {
      bf16x8 pf = *reinterpret_cast<const bf16x8*>(
          &Ps[wave][1][lmod * 72 + ks * 32 + lgrp * 8]);
#pragma unroll
      for (int dhg = 0; dhg < 4; ++dhg) {
        bf16x8 vf = *reinterpret_cast<const bf16x8*>(
            &Vs[(dhg * 16 + lmod) * 72 + ks * 32 + lgrp * 8]);
        oacc[dhg] = __builtin_amdgcn_mfma_f32_16x16x32_bf16(pf, vf, oacc[dhg], 0, 0, 0);
      }
    }
    __builtin_amdgcn_s_setprio(0);
  };

  // dual step: both q-tiles share every K/V fragment (j <= p; diag_lo = j==p)
  auto step_dual = [&](bool diag_lo) {
    f32x4 sl[4], sh[4];
    __builtin_amdgcn_s_setprio(1);
#pragma unroll
    for (int cg = 0; cg < 4; ++cg) {
      f32x4 al = {}, ah = {};
#pragma unroll
      for (int ks = 0; ks < 2; ++ks) {
        bf16x8 kf = *reinterpret_cast<const bf16x8*>(
            &Ks[(cg * 16 + lmod) * 72 + ks * 32 + lgrp * 8]);
        al = __builtin_amdgcn_mfma_f32_16x16x32_bf16(qfl[ks], kf, al, 0, 0, 0);
        ah = __builtin_amdgcn_mfma_f32_16x16x32_bf16(qfh[ks], kf, ah, 0, 0, 0);
      }
      sl[cg] = al; sh[cg] = ah;
    }
    __builtin_amdgcn_s_setprio(0);
    if (diag_lo) mask_diag(sl);          // hi tile never diagonal here (p < jmax)
#pragma unroll
    for (int cg = 0; cg < 4; ++cg)
#pragma unroll
      for (int r = 0; r < 4; ++r) {
        sl[cg][r] = exp2f(sl[cg][r]);
        sh[cg][r] = exp2f(sh[cg][r]);
      }
#pragma unroll
    for (int r = 0; r < 4; ++r) {
      ll[r] += (sl[0][r] + sl[1][r]) + (sl[2][r] + sl[3][r]);
      lh[r] += (sh[0][r] + sh[1][r]) + (sh[2][r] + sh[3][r]);
    }
#pragma unroll
    for (int cg = 0; cg < 4; ++cg)
#pragma unroll
      for (int r = 0; r < 4; ++r) {
        Ps[wave][0][(lgrp * 4 + r) * 72 + cg * 16 + lmod] = f2bf_hw(sl[cg][r]);
        Ps[wave][1][(lgrp * 4 + r) * 72 + cg * 16 + lmod] = f2bf_hw(sh[cg][r]);
      }
    __builtin_amdgcn_s_setprio(1);
#pragma unroll
    for (int ks = 0; ks < 2; ++ks) {
      bf16x8 pfl = *reinterpret_cast<const bf16x8*>(
          &Ps[wave][0][lmod * 72 + ks * 32 + lgrp * 8]);
      bf16x8 pfh = *reinterpret_cast<const bf16x8*>(
          &Ps[wave][1][lmod * 72 + ks * 32 + lgrp * 8]);
#pragma unroll
      for (int dhg = 0; dhg < 4; ++dhg) {
        bf16x8 vf = *reinterpret_cast<const bf16x8*>(
            &Vs[(dhg * 16 + lmod) * 72 + ks * 32 + lgrp * 8]);
        ol[dhg] = __builtin_amdgcn_mfma_f32_16x16x32_bf16(pfl, vf, ol[dhg], 0, 0, 0);
        oh[dhg] = __builtin_amdgcn_mfma_f32_16x16x32_bf16(pfh, vf, oh[dhg], 0, 0, 0);
      }
    }
    __builtin_amdgcn_s_setprio(0);
  };

  load_tile(0);
  for (int j = 0; j <= jmax; ++j) {
    __syncthreads();
    write_tile();
    __syncthreads();
    if (j < jmax) load_tile(j + 1);
    if (j <= p) step_dual(j == p);       // block-uniform branch
    else step(qfh, oh, lh, j == jmax);
  }

#pragma unroll
  for (int m = 1; m <= 8; m <<= 1)
#pragma unroll
    for (int r = 0; r < 4; ++r) {
      ll[r] += __shfl_xor(ll[r], m);
      lh[r] += __shfl_xor(lh[r], m);
    }

#pragma unroll
  for (int dhg = 0; dhg < 4; ++dhg) {
    const int col = h * 64 + dhg * 16 + lmod;
#pragma unroll
    for (int r = 0; r < 4; ++r) {
      Og[(xrow0 + qlo + lgrp * 4 + r) * 1024 + col] = f2bf_hw(ol[dhg][r] / ll[r]);
      Og[(xrow0 + qhi + lgrp * 4 + r) * 1024 + col] = f2bf_hw(oh[dhg][r] / lh[r]);
    }
  }
}

// ---------------- launch ----------------

extern "C" void kernel_launch(void* const* d_in, const int* in_sizes, int n_in,
                              void* d_out, int out_size, void* d_ws, size_t ws_size,
                              hipStream_t stream) {
  const float* x  = (const float*)d_in[0];
  const float* Wq = (const float*)d_in[1];
  const float* bq = (const float*)d_in[2];
  const float* Wk = (const float*)d_in[3];
  const float* bk = (const float*)d_in[4];
  const float* Wv = (const float*)d_in[5];
  const float* bv = (const float*)d_in[6];
  const float* Wp = (const float*)d_in[7];
  const float* bp = (const float*)d_in[8];
  float* out = (float*)d_out;

  char* ws = (char*)d_ws;
  ushort_t* XB    = (ushort_t*)(ws);                  // 8MB; reused as ctx
  ushort_t* WQKVT = (ushort_t*)(ws + ( 8ull << 20));  // 6MB [3072][1024]
  ushort_t* WPT   = (ushort_t*)(ws + (14ull << 20));  // 2MB [1024][1024]
  ushort_t* QKVB  = (ushort_t*)(ws + (16ull << 20));  // 24MB [4096][3072] (V region unused)
  ushort_t* VT    = (ushort_t*)(ws + (40ull << 20));  // 8MB [64bh][64d][1024t]

  cvt_fused_kernel<<<8192, 256, 0, stream>>>(x, Wq, Wk, Wv, Wp, XB, WQKVT, WPT);
  gemm_qkv128_kernel<<<768, 256, 0, stream>>>(XB, WQKVT, bq, bk, bv, QKVB, VT);
  attn_kernel<<<512, 256, 0, stream>>>(QKVB, VT, XB);
  gemm_proj_kernel<<<512, 256, 0, stream>>>(XB, WPT, bp, out);
}